// Round 2
// baseline (242.179 us; speedup 1.0000x reference)
//
#include <hip/hip_runtime.h>

#define H 512
#define W 512
#define K 5
#define PAD 2
#define ROWS 8            // output rows per thread (sliding window)
#define NR (ROWS + K - 1) // 12 input rows per thread
#define XPT 4             // output cols per thread (one float4)
#define PF 3              // prefetch distance in rows (9 loads in flight)
#define DEPTH 4           // register ring depth (PF+1)

typedef float vf4 __attribute__((ext_vector_type(4)));

// Latency-bound fix (round-1 counters: hbm 35%, VALUBusy 31%, occ 38% -- all
// low): (1) rows are loaded BRANCHLESS via clamped addresses + 0/1 row mask,
// so loads are unconditional and hoistable; (2) explicit 3-row register-ring
// prefetch keeps ~9 loads in flight per wave (compiler emits counted vmcnt
// instead of per-row drains); (3) ROWS=8 doubles the grid to 4096 blocks for
// 2x wave over-subscription. Vertical re-read (1.5x raw) is L3-absorbed
// (round-1: FETCH 91.7MB < input 134MB), so HBM traffic stays ~input+output.
// All ring/acc indices are compile-time after full unroll (no scratch).
__global__ __launch_bounds__(256, 4) void conv5x5_kernel(
    const float* __restrict__ X, const float* __restrict__ ker,
    float* __restrict__ out)
{
    const int tx  = threadIdx.x;                      // 0..63
    const int xb  = (blockIdx.x * 64 + tx) * XPT;     // 0,4,...,508
    const int y0  = blockIdx.y * (4 * ROWS) + threadIdx.y * ROWS;
    const int img = blockIdx.z;                       // 0..127

    const float* Xp = X   + (size_t)img * H * W;
    float*       Op = out + (size_t)img * H * W;

    float kk[K][K];
    #pragma unroll
    for (int i = 0; i < K; ++i)
        #pragma unroll
        for (int j = 0; j < K; ++j)
            kk[i][j] = ker[i * K + j];

    const int q  = xb >> 2;                           // float4 col index 0..127
    const int qL = (q == 0) ? 0 : q - 1;              // clamped: always in-bounds
    const int qR = (q == W / 4 - 1) ? q : q + 1;
    const float mLo = (q == 0) ? 0.f : 1.f;           // zero v[0],v[1] at left edge
    const float mHi = (q == W / 4 - 1) ? 0.f : 1.f;   // zero v[6],v[7] at right edge

    // register ring of prefetched rows (indices compile-time after unroll)
    vf4 bl[DEPTH], bm[DEPTH], br[DEPTH];

    // prologue: issue loads for rows 0..PF-1 (clamped, unconditional)
    #pragma unroll
    for (int r = 0; r < PF; ++r) {
        const int yr = y0 - PAD + r;
        const int yc = yr < 0 ? 0 : (yr > H - 1 ? H - 1 : yr);
        const vf4* rp = (const vf4*)(Xp + (size_t)yc * W);
        bl[r] = rp[qL];  bm[r] = rp[q];  br[r] = rp[qR];
    }

    float acc[K][XPT];
    #pragma unroll
    for (int p = 0; p < K; ++p)
        #pragma unroll
        for (int j = 0; j < XPT; ++j)
            acc[p][j] = 0.f;

    #pragma unroll
    for (int r = 0; r < NR; ++r) {                    // 12 input rows
        // prefetch row r+PF into the ring (unconditional, clamped)
        if (r + PF < NR) {
            const int rr = r + PF;
            const int yr = y0 - PAD + rr;
            const int yc = yr < 0 ? 0 : (yr > H - 1 ? H - 1 : yr);
            const vf4* rp = (const vf4*)(Xp + (size_t)yc * W);
            bl[rr % DEPTH] = rp[qL];
            bm[rr % DEPTH] = rp[q];
            br[rr % DEPTH] = rp[qR];
        }

        // consume row r: zero out-of-image rows via 0/1 multiply (no branch)
        const int yr = y0 - PAD + r;
        const float mR = (yr >= 0 && yr < H) ? 1.f : 0.f;
        const float mA = mLo * mR;
        const float mC = mHi * mR;
        const vf4 Lv = bl[r % DEPTH];
        const vf4 Mv = bm[r % DEPTH];
        const vf4 Rv = br[r % DEPTH];

        // window v[0..7] = input cols xb-2 .. xb+5
        float v[8];
        v[0] = Lv.z * mA;  v[1] = Lv.w * mA;
        v[2] = Mv.x * mR;  v[3] = Mv.y * mR;
        v[4] = Mv.z * mR;  v[5] = Mv.w * mR;
        v[6] = Rv.x * mC;  v[7] = Rv.y * mC;

        // input row r feeds kernel-row kr of output row o = r - kr.
        // Per output row: kr = 0..4, c = 0..4 -- same order as before.
        #pragma unroll
        for (int kr = 0; kr < K; ++kr) {
            const int o = r - kr;
            if (o >= 0 && o < ROWS) {
                const int pa = o % K;                 // compile-time
                #pragma unroll
                for (int c = 0; c < K; ++c)
                    #pragma unroll
                    for (int j = 0; j < XPT; ++j)
                        acc[pa][j] = fmaf(v[j + c], kk[kr][c], acc[pa][j]);
            }
        }

        // output row o = r-4 just received its last (kr=4) contribution
        if (r >= K - 1) {
            const int o  = r - (K - 1);
            const int pa = o % K;                     // compile-time
            vf4 st = {acc[pa][0], acc[pa][1], acc[pa][2], acc[pa][3]};
            __builtin_nontemporal_store(st, (vf4*)(Op + (size_t)(y0 + o) * W + xb));
            #pragma unroll
            for (int j = 0; j < XPT; ++j)
                acc[pa][j] = 0.f;                     // slot reused next row
        }
    }
}

extern "C" void kernel_launch(void* const* d_in, const int* in_sizes, int n_in,
                              void* d_out, int out_size, void* d_ws, size_t ws_size,
                              hipStream_t stream) {
    const float* X   = (const float*)d_in[0];
    const float* ker = (const float*)d_in[1];
    float* out = (float*)d_out;

    dim3 block(64, 4, 1);
    dim3 grid(W / (64 * XPT), H / (4 * ROWS), 4 * 32);  // (2, 16, 128)
    hipLaunchKernelGGL(conv5x5_kernel, grid, block, 0, stream, X, ker, out);
}

// Round 3
// 233.224 us; speedup vs baseline: 1.0384x; 1.0384x over previous
//
#include <hip/hip_runtime.h>

#define H 512
#define W 512
#define K 5
#define PAD 2
#define RPT 4             // output rows per thread
#define XPT 4             // output cols per thread (one float4)
#define NR (RPT + K - 1)  // 8 input rows per thread

typedef float vf4 __attribute__((ext_vector_type(4)));
typedef float vf2 __attribute__((ext_vector_type(2)));

// Round-2 post-mortem: the software prefetch ring was compiled away
// (VGPR=52 proves the loads were re-sunk to point-of-use); per-row
// load->drain->fma serialization left all pipes <40%. This version makes
// the overlap structural: ALL 8 rows are loaded into named registers
// BEFORE any FMA (24 independent loads in flight per wave; compiler must
// emit counted vmcnt as row 0 is consumed while rows 1-7 fly). Halo loads
// are float2 (just cols xb-2,xb-1 / xb+4,xb+5), cutting held VGPRs to
// 64 and L1 traffic by 33% vs three float4s. Rows are branchless:
// clamped address + 0/1 mask (identical v[] values / fma order as the
// passing rounds). RPT=4 restores the 8192-block grid (4x wave
// over-subscription) that round 0 showed beats 8/16-row tiles.
__global__ __launch_bounds__(256, 4) void conv5x5_kernel(
    const float* __restrict__ X, const float* __restrict__ ker,
    float* __restrict__ out)
{
    const int tx  = threadIdx.x;                      // 0..63
    const int xb  = (blockIdx.x * 64 + tx) * XPT;     // 0,4,...,508
    const int y0  = blockIdx.y * (4 * RPT) + threadIdx.y * RPT;
    const int img = blockIdx.z;                       // 0..127

    const float* Xp = X   + (size_t)img * H * W;
    float*       Op = out + (size_t)img * H * W;

    // kernel coeffs: uniform address -> compiler scalarizes into SGPRs
    float kk[K][K];
    #pragma unroll
    for (int i = 0; i < K; ++i)
        #pragma unroll
        for (int j = 0; j < K; ++j)
            kk[i][j] = ker[i * K + j];

    // halo addresses, clamped in-bounds (8B-aligned: xb is a multiple of 4)
    const int xL = (xb == 0) ? 0 : xb - 2;            // cols xb-2, xb-1
    const int xR = (xb == W - XPT) ? xb : xb + 4;     // cols xb+4, xb+5
    const float mLo = (xb == 0) ? 0.f : 1.f;
    const float mHi = (xb == W - XPT) ? 0.f : 1.f;

    // ---- load phase: all 8 rows issued before any consumption ----
    vf2 hl[NR];  vf4 mm[NR];  vf2 hr[NR];
    float rmask[NR];
    #pragma unroll
    for (int r = 0; r < NR; ++r) {
        const int yr = y0 - PAD + r;
        const int yc = yr < 0 ? 0 : (yr > H - 1 ? H - 1 : yr);
        rmask[r] = (yr >= 0 && yr < H) ? 1.f : 0.f;
        const float* rp = Xp + (size_t)yc * W;
        hl[r] = *(const vf2*)(rp + xL);
        mm[r] = *(const vf4*)(rp + xb);
        hr[r] = *(const vf2*)(rp + xR);
    }

    float acc[RPT][XPT];
    #pragma unroll
    for (int o = 0; o < RPT; ++o)
        #pragma unroll
        for (int j = 0; j < XPT; ++j)
            acc[o][j] = 0.f;

    // ---- compute phase: consume rows in order (vmcnt counts down) ----
    #pragma unroll
    for (int r = 0; r < NR; ++r) {
        const float mR = rmask[r];
        const float mA = mLo * mR;
        const float mC = mHi * mR;
        // window v[0..7] = input cols xb-2 .. xb+5 (same values as before)
        float v[8];
        v[0] = hl[r].x * mA;  v[1] = hl[r].y * mA;
        v[2] = mm[r].x * mR;  v[3] = mm[r].y * mR;
        v[4] = mm[r].z * mR;  v[5] = mm[r].w * mR;
        v[6] = hr[r].x * mC;  v[7] = hr[r].y * mC;

        #pragma unroll
        for (int o = 0; o < RPT; ++o) {
            const int kr = r - o;
            if (kr >= 0 && kr < K) {
                #pragma unroll
                for (int c = 0; c < K; ++c)
                    #pragma unroll
                    for (int j = 0; j < XPT; ++j)
                        acc[o][j] = fmaf(v[j + c], kk[kr][c], acc[o][j]);
            }
        }
    }

    #pragma unroll
    for (int o = 0; o < RPT; ++o) {
        vf4 st = {acc[o][0], acc[o][1], acc[o][2], acc[o][3]};
        __builtin_nontemporal_store(st, (vf4*)(Op + (size_t)(y0 + o) * W + xb));
    }
}

extern "C" void kernel_launch(void* const* d_in, const int* in_sizes, int n_in,
                              void* d_out, int out_size, void* d_ws, size_t ws_size,
                              hipStream_t stream) {
    const float* X   = (const float*)d_in[0];
    const float* ker = (const float*)d_in[1];
    float* out = (float*)d_out;

    dim3 block(64, 4, 1);
    dim3 grid(W / (64 * XPT), H / (4 * RPT), 4 * 32);  // (2, 32, 128)
    hipLaunchKernelGGL(conv5x5_kernel, grid, block, 0, stream, X, ker, out);
}